// Round 22
// baseline (168.851 us; speedup 1.0000x reference)
//
#include <hip/hip_runtime.h>

// TransformerClassification: 2-layer PyG TransformerConv GNN on MI355X.
// Round 22: scatter phase widened — SC_EPB 4096->1024 (196->782 blocks; r21
// had <1 scatter block per CU so long serial scatter blocks set the fused
// kernel's critical path). Per-thread edge records cached in registers during
// the hist pass (no 2nd global read pass). Rest identical to r21 (135.7us).

#define N_NODES 50000
#define N_EDGES 800000
#define IN_F    128
#define HC      64      // heads*ch layer1
#define NH      4
#define CH      16
#define OUTF    7

#define DPB 100                        // dsts per bucket
#define NBK (N_NODES / DPB)            // 500 buckets
#define SC_EPB 1024
#define SCA_BLOCKS ((N_EDGES + SC_EPB - 1) / SC_EPB)   // 782
#define P1_TILE 32
#define P1_BLOCKS ((N_NODES + P1_TILE - 1) / P1_TILE)  // 1563

typedef __attribute__((ext_vector_type(8))) short bf16x8;
typedef __attribute__((ext_vector_type(4))) float f32x4;

__device__ __forceinline__ unsigned short f2bf(float f) {
    unsigned u = __float_as_uint(f);
    unsigned r = u + 0x7FFFu + ((u >> 16) & 1u);   // round-to-nearest-even
    return (unsigned short)(r >> 16);
}
__device__ __forceinline__ float bflo(unsigned u) { return __uint_as_float(u << 16); }
__device__ __forceinline__ float bfhi(unsigned u) { return __uint_as_float(u & 0xFFFF0000u); }
__device__ __forceinline__ float elu_fast(float x) {
    return x > 0.f ? x : __expf(x) - 1.f;
}

// ---------------- DPP helpers ----------------
__device__ __forceinline__ float dpp_add4(float x) {   // sum within HW quad
    int t;
    t = __builtin_amdgcn_update_dpp(0, __float_as_int(x), 0xB1, 0xF, 0xF, false);
    x += __int_as_float(t);
    t = __builtin_amdgcn_update_dpp(0, __float_as_int(x), 0x4E, 0xF, 0xF, false);
    x += __int_as_float(t);
    return x;
}
__device__ __forceinline__ float dpp_add16(float x) {
    int t;
    t = __builtin_amdgcn_update_dpp(0, __float_as_int(x), 0xB1, 0xF, 0xF, false);
    x += __int_as_float(t);
    t = __builtin_amdgcn_update_dpp(0, __float_as_int(x), 0x4E, 0xF, 0xF, false);
    x += __int_as_float(t);
    t = __builtin_amdgcn_update_dpp(0, __float_as_int(x), 0x124, 0xF, 0xF, false);
    x += __int_as_float(t);
    t = __builtin_amdgcn_update_dpp(0, __float_as_int(x), 0x128, 0xF, 0xF, false);
    x += __int_as_float(t);
    return x;
}
__device__ __forceinline__ float dpp_max16(float x) {
    int t;
    t = __builtin_amdgcn_update_dpp(0, __float_as_int(x), 0xB1, 0xF, 0xF, false);
    x = fmaxf(x, __int_as_float(t));
    t = __builtin_amdgcn_update_dpp(0, __float_as_int(x), 0x4E, 0xF, 0xF, false);
    x = fmaxf(x, __int_as_float(t));
    t = __builtin_amdgcn_update_dpp(0, __float_as_int(x), 0x124, 0xF, 0xF, false);
    x = fmaxf(x, __int_as_float(t));
    t = __builtin_amdgcn_update_dpp(0, __float_as_int(x), 0x128, 0xF, 0xF, false);
    x = fmaxf(x, __int_as_float(t));
    return x;
}

// ---------------------------------------------------------------- convert W -> Wt bf16 (+zero bcnt)
__global__ __launch_bounds__(256) void convert_w_kernel(
    const float* __restrict__ Wq, const float* __restrict__ Wk,
    const float* __restrict__ Wv, const float* __restrict__ Ws,
    unsigned short* __restrict__ Wt, int* __restrict__ bcnt)
{
    int i = blockIdx.x * 256 + threadIdx.x;   // 4*64*128 = 32768
    if (blockIdx.x < 2) {
        int j = blockIdx.x * 256 + threadIdx.x;
        if (j < NBK) bcnt[j] = 0;
    }
    if (i >= 4 * HC * IN_F) return;
    int m   = i >> 13;          // /8192
    int col = (i >> 7) & 63;
    int k   = i & 127;
    const float* W = (m == 0) ? Wq : (m == 1) ? Wk : (m == 2) ? Wv : Ws;
    Wt[i] = f2bf(W[k * HC + col]);
}

// ---------------------------------------------------------------- bucket histogram (LDS-aggregated)
__global__ __launch_bounds__(256) void bhist_kernel(
    const int* __restrict__ ei, int* __restrict__ bcnt)
{
    __shared__ int cnt[NBK];
    const int t = threadIdx.x;
    const int e0 = blockIdx.x * SC_EPB;
    const int e1 = (e0 + SC_EPB < N_EDGES) ? e0 + SC_EPB : N_EDGES;
    for (int j = t; j < NBK; j += 256) cnt[j] = 0;
    __syncthreads();
    for (int e = e0 + t; e < e1; e += 256)
        atomicAdd(&cnt[ei[N_EDGES + e] / DPB], 1);
    __syncthreads();
    for (int j = t; j < NBK; j += 256)
        if (cnt[j]) atomicAdd(&bcnt[j], cnt[j]);
}

// ---------------------------------------------------------------- bucket scan (1 block, 500 elems)
__global__ __launch_bounds__(256) void bscan_kernel(
    const int* __restrict__ bcnt, int* __restrict__ bofs2, int* __restrict__ bcur)
{
    __shared__ int partial[256];
    const int t = threadIdx.x;
    const int b0 = t * 2;
    int c0 = (b0     < NBK) ? bcnt[b0]     : 0;
    int c1 = (b0 + 1 < NBK) ? bcnt[b0 + 1] : 0;
    int s = c0 + c1;
    partial[t] = s;
    __syncthreads();
    for (int d = 1; d < 256; d <<= 1) {
        int u = (t >= d) ? partial[t - d] : 0;
        __syncthreads();
        partial[t] += u;
        __syncthreads();
    }
    int run = partial[t] - s;
    if (b0 < NBK)     { bofs2[b0]     = run;      bcur[b0]     = run; }
    if (b0 + 1 < NBK) { bofs2[b0 + 1] = run + c0; bcur[b0 + 1] = run + c0; }
    if (t == 255) bofs2[NBK] = N_EDGES;
}

// ---------------------------------------------------------------- fused: scatterA (blocks 0..781) | proj1 MFMA
// Scatter: 1024 edges/block, 4 edges/thread cached in registers (single
// global read pass). proj: 32 nodes x 256 cols per block.
__global__ __launch_bounds__(256) void proj1_scatterA_kernel(
    const float* __restrict__ x, const unsigned short* __restrict__ Wt,
    const float* __restrict__ bq, const float* __restrict__ bk,
    const float* __restrict__ bv, const float* __restrict__ bs,
    unsigned short* __restrict__ q1b, unsigned short* __restrict__ kv1,
    unsigned short* __restrict__ s1b,
    const int* __restrict__ ei, const float* __restrict__ ea,
    int* __restrict__ bcur, uint2* __restrict__ etmp)
{
    __shared__ unsigned short xs[P1_TILE][136];
    __shared__ int cnt[NBK];
    __shared__ int base[NBK];
    const int t = threadIdx.x;

    if (blockIdx.x < SCA_BLOCKS) {
        const int e0 = blockIdx.x * SC_EPB;
        const int e1 = (e0 + SC_EPB < N_EDGES) ? e0 + SC_EPB : N_EDGES;
        int   dsts[4];
        uint2 recs[4];
        int   nj = 0;
        for (int j = t; j < NBK; j += 256) cnt[j] = 0;
        __syncthreads();
        for (int e = e0 + t; e < e1; e += 256) {
            int d = ei[N_EDGES + e];
            int s = ei[e];
            dsts[nj] = d;
            recs[nj].x = (unsigned)s | ((unsigned)d << 16);
            recs[nj].y = (unsigned)f2bf(ea[(size_t)e * 2])
                       | ((unsigned)f2bf(ea[(size_t)e * 2 + 1]) << 16);
            nj++;
            atomicAdd(&cnt[d / DPB], 1);
        }
        __syncthreads();
        for (int j = t; j < NBK; j += 256) {
            int c = cnt[j];
            if (c) base[j] = atomicAdd(&bcur[j], c);
            cnt[j] = 0;
        }
        __syncthreads();
        for (int j = 0; j < nj; j++) {
            int b = dsts[j] / DPB;
            int li = atomicAdd(&cnt[b], 1);
            etmp[base[b] + li] = recs[j];
        }
        return;
    }

    const int w = t >> 6, lane = t & 63;
    const int n0 = (blockIdx.x - SCA_BLOCKS) * P1_TILE;
    const int col16 = lane & 15, kg = lane >> 4;

    // B-fragments: 4 k-chunks x 4 n-tiles (reused across both M-tiles)
    bf16x8 bfrag[4][4];
#pragma unroll
    for (int tt = 0; tt < 4; tt++) {
        const unsigned short* bp = Wt + ((size_t)(w * 64 + tt * 16 + col16) * IN_F) + 8 * kg;
#pragma unroll
        for (int kc = 0; kc < 4; kc++)
            bfrag[kc][tt] = *(const bf16x8*)(bp + kc * 32);
    }

    // stage 32 x-rows as bf16 (1 row-sixteenth per thread), guard tail
    {
        int row = t >> 3, cg = (t & 7) * 16;
        uint4 pk0 = make_uint4(0, 0, 0, 0), pk1 = make_uint4(0, 0, 0, 0);
        if (n0 + row < N_NODES) {
            const float* xp = x + (size_t)(n0 + row) * IN_F + cg;
            float4 f0 = *(const float4*)xp;
            float4 f1 = *(const float4*)(xp + 4);
            float4 f2 = *(const float4*)(xp + 8);
            float4 f3 = *(const float4*)(xp + 12);
            pk0.x = f2bf(f0.x) | ((unsigned)f2bf(f0.y) << 16);
            pk0.y = f2bf(f0.z) | ((unsigned)f2bf(f0.w) << 16);
            pk0.z = f2bf(f1.x) | ((unsigned)f2bf(f1.y) << 16);
            pk0.w = f2bf(f1.z) | ((unsigned)f2bf(f1.w) << 16);
            pk1.x = f2bf(f2.x) | ((unsigned)f2bf(f2.y) << 16);
            pk1.y = f2bf(f2.z) | ((unsigned)f2bf(f2.w) << 16);
            pk1.z = f2bf(f3.x) | ((unsigned)f2bf(f3.y) << 16);
            pk1.w = f2bf(f3.z) | ((unsigned)f2bf(f3.w) << 16);
        }
        *(uint4*)&xs[row][cg]     = pk0;
        *(uint4*)&xs[row][cg + 8] = pk1;
    }
    __syncthreads();

    f32x4 acc[2][4] = { { {0,0,0,0}, {0,0,0,0}, {0,0,0,0}, {0,0,0,0} },
                        { {0,0,0,0}, {0,0,0,0}, {0,0,0,0}, {0,0,0,0} } };
#pragma unroll
    for (int kc = 0; kc < 4; kc++) {
        bf16x8 a0 = *(const bf16x8*)&xs[col16][kc * 32 + 8 * kg];
        bf16x8 a1 = *(const bf16x8*)&xs[16 + col16][kc * 32 + 8 * kg];
#pragma unroll
        for (int tt = 0; tt < 4; tt++) {
            acc[0][tt] = __builtin_amdgcn_mfma_f32_16x16x32_bf16(a0, bfrag[kc][tt], acc[0][tt], 0, 0, 0);
            acc[1][tt] = __builtin_amdgcn_mfma_f32_16x16x32_bf16(a1, bfrag[kc][tt], acc[1][tt], 0, 0, 0);
        }
    }

    if (w == 0 || w == 3) {
        const float* Bm = (w == 0) ? bq : bs;
        unsigned short* Om = (w == 0) ? q1b : s1b;
#pragma unroll
        for (int mt = 0; mt < 2; mt++)
#pragma unroll
        for (int tt = 0; tt < 4; tt++) {
            int col = tt * 16 + col16;
            float bias = Bm[col];
#pragma unroll
            for (int r = 0; r < 4; r++) {
                int node = n0 + mt * 16 + kg * 4 + r;
                if (node < N_NODES)
                    Om[(size_t)node * HC + col] = f2bf(acc[mt][tt][r] + bias);
            }
        }
    } else {
        const float* Bm = (w == 1) ? bk : bv;
        const int cbase = (w == 1) ? 0 : 64;
#pragma unroll
        for (int mt = 0; mt < 2; mt++)
#pragma unroll
        for (int tt = 0; tt < 4; tt++) {
            int col = tt * 16 + col16;
            float bias = Bm[col];
#pragma unroll
            for (int r = 0; r < 4; r++) {
                int node = n0 + mt * 16 + kg * 4 + r;
                if (node < N_NODES)
                    kv1[(size_t)node * 128 + cbase + col] = f2bf(acc[mt][tt][r] + bias);
            }
        }
    }
}

// ---------------------------------------------------------------- scatter phase B: per-dst offs + exact placement
__global__ __launch_bounds__(256) void sortB_kernel(
    const int* __restrict__ bofs2, const uint2* __restrict__ etmp,
    uint2* __restrict__ erec, int* __restrict__ offs)
{
    __shared__ int deg[DPB];
    __shared__ int pre[DPB];
    __shared__ int cur[DPB];
    const int t = threadIdx.x;
    const int b = blockIdx.x;
    const int dlo = b * DPB;
    const int rbeg = bofs2[b], rend = bofs2[b + 1];

    if (t < DPB) deg[t] = 0;
    __syncthreads();
    for (int i = rbeg + t; i < rend; i += 256)
        atomicAdd(&deg[(int)(etmp[i].x >> 16) - dlo], 1);
    __syncthreads();
    if (t < DPB) pre[t] = deg[t];
    __syncthreads();
#pragma unroll
    for (int d = 1; d < DPB; d <<= 1) {
        int u = (t >= d && t < DPB) ? pre[t - d] : 0;
        __syncthreads();
        if (t < DPB) pre[t] += u;
        __syncthreads();
    }
    if (t < DPB) {
        int o = rbeg + pre[t] - deg[t];
        offs[dlo + t] = o;
        cur[t] = o;
    }
    if (b == NBK - 1 && t == 0) offs[N_NODES] = N_EDGES;
    __syncthreads();
    for (int i = rbeg + t; i < rend; i += 256) {
        uint2 r = etmp[i];
        int d = (int)(r.x >> 16) - dlo;
        int pos = atomicAdd(&cur[d], 1);
        uint2 o;
        o.x = r.x & 0xFFFFu;   // src
        o.y = r.y;             // ea bf16x2
        erec[pos] = o;
    }
}

// ---------------------------------------------------------------- layer1 attention: one wave per dst node
__global__ __launch_bounds__(256) void attn1_kernel(
    const int* __restrict__ offs, const uint2* __restrict__ erec,
    const float* __restrict__ We,
    const unsigned short* __restrict__ q1b, const unsigned short* __restrict__ kv1,
    const unsigned short* __restrict__ s1b, float* __restrict__ h)
{
    int n    = (blockIdx.x * 256 + threadIdx.x) >> 6;
    int lane = threadIdx.x & 63;
    if (n >= N_NODES) return;
    const int g = lane >> 4;     // edge slot 0..3
    const int s = lane & 15;     // channel quad: channels 4s..4s+3

    uint2 qraw = *(const uint2*)(q1b + ((size_t)n << 6) + (s << 2));
    const float4 qv = make_float4(bflo(qraw.x), bfhi(qraw.x),
                                  bflo(qraw.y), bfhi(qraw.y));
    const float4 We0 = *(const float4*)(We + s * 4);
    const float4 We1 = *(const float4*)(We + HC + s * 4);

    float qw0 = dpp_add4(qv.x*We0.x + qv.y*We0.y + qv.z*We0.z + qv.w*We0.w);
    float qw1 = dpp_add4(qv.x*We1.x + qv.y*We1.y + qv.z*We1.z + qv.w*We1.w);

    const int beg = offs[n], end = offs[n + 1];
    float m = -3.402823466e38f, l = 0.f, A0 = 0.f, A1 = 0.f;
    float4 acc = make_float4(0.f, 0.f, 0.f, 0.f);

    for (int base = beg; base < end; base += 4) {
        int i = base + g;
        bool valid = (i < end);
        uint2 r = erec[valid ? i : beg];
        int src = (int)r.x;
        float ea0 = bflo(r.y), ea1 = bfhi(r.y);
        const unsigned short* kvp = kv1 + ((size_t)src << 7) + (s << 2);
        uint2 kraw = *(const uint2*)kvp;
        uint2 vraw = *(const uint2*)(kvp + 64);
        float k0 = bflo(kraw.x), k1 = bfhi(kraw.x);
        float k2 = bflo(kraw.y), k3 = bfhi(kraw.y);
        float dot = qv.x*k0 + qv.y*k1 + qv.z*k2 + qv.w*k3;
        dot = dpp_add4(dot);                      // head dot (16 channels)
        float logit = valid ? (dot + ea0 * qw0 + ea1 * qw1) * 0.25f
                            : -3.402823466e38f;   // 1/sqrt(16)
        if (__any(logit > m + 8.f)) {             // defer-max: rare path
            float mn = fmaxf(m, logit);
            float sm = __expf(m - mn);
            l *= sm; A0 *= sm; A1 *= sm;
            acc.x *= sm; acc.y *= sm; acc.z *= sm; acc.w *= sm;
            m = mn;
        }
        float pe = valid ? __expf(logit - m) : 0.f;   // bounded by e^8
        l += pe;
        float v0 = bflo(vraw.x), v1 = bfhi(vraw.x);
        float v2 = bflo(vraw.y), v3 = bfhi(vraw.y);
        acc.x += pe * v0; acc.y += pe * v1;
        acc.z += pe * v2; acc.w += pe * v3;
        A0 += pe * ea0;  A1 += pe * ea1;
    }

    if (end > beg) {
        float M = fmaxf(m, __shfl_xor(m, 16));
        M = fmaxf(M, __shfl_xor(M, 32));
        float sc = __expf(m - M);                 // empty group: -inf -> 0
        l *= sc; A0 *= sc; A1 *= sc;
        acc.x *= sc; acc.y *= sc; acc.z *= sc; acc.w *= sc;
        l  += __shfl_xor(l, 16);   l  += __shfl_xor(l, 32);
        A0 += __shfl_xor(A0, 16);  A0 += __shfl_xor(A0, 32);
        A1 += __shfl_xor(A1, 16);  A1 += __shfl_xor(A1, 32);
        acc.x += __shfl_xor(acc.x, 16); acc.x += __shfl_xor(acc.x, 32);
        acc.y += __shfl_xor(acc.y, 16); acc.y += __shfl_xor(acc.y, 32);
        acc.z += __shfl_xor(acc.z, 16); acc.z += __shfl_xor(acc.z, 32);
        acc.w += __shfl_xor(acc.w, 16); acc.w += __shfl_xor(acc.w, 32);
        if (lane < 16) {
            float inv = 1.f / l;
            uint2 sraw = *(const uint2*)(s1b + ((size_t)n << 6) + (s << 2));
            float4 o;
            o.x = elu_fast((acc.x + A0 * We0.x + A1 * We1.x) * inv + bflo(sraw.x));
            o.y = elu_fast((acc.y + A0 * We0.y + A1 * We1.y) * inv + bfhi(sraw.x));
            o.z = elu_fast((acc.z + A0 * We0.z + A1 * We1.z) * inv + bflo(sraw.y));
            o.w = elu_fast((acc.w + A0 * We0.w + A1 * We1.w) * inv + bfhi(sraw.y));
            *(float4*)(h + (size_t)n * HC + s * 4) = o;
        }
    } else if (lane < 16) {
        uint2 sraw = *(const uint2*)(s1b + ((size_t)n << 6) + (s << 2));
        float4 o;
        o.x = elu_fast(bflo(sraw.x));
        o.y = elu_fast(bfhi(sraw.x));
        o.z = elu_fast(bflo(sraw.y));
        o.w = elu_fast(bfhi(sraw.y));
        *(float4*)(h + (size_t)n * HC + s * 4) = o;
    }
}

// ---------------------------------------------------------------- layer2 node projections (64 -> 28), thread-per-node
__global__ __launch_bounds__(256) void proj2_kernel(
    const float* __restrict__ h,
    const float* __restrict__ Wq, const float* __restrict__ bq,
    const float* __restrict__ Wk, const float* __restrict__ bk,
    const float* __restrict__ Wv, const float* __restrict__ bv,
    const float* __restrict__ Ws, const float* __restrict__ bs,
    float* __restrict__ q2p, float* __restrict__ kv2, float* __restrict__ s2p)
{
    __shared__ float Wsm[HC][4][8];   // 8 KB
    __shared__ float Bsm[4][8];
    const int t = threadIdx.x;

    for (int j = t; j < HC * 28; j += 256) {
        int i = j / 28, r = j % 28, mtx = r / 7, c = r % 7;
        const float* W = (mtx == 0) ? Wq : (mtx == 1) ? Wk : (mtx == 2) ? Wv : Ws;
        Wsm[i][mtx][c] = W[i * OUTF + c];
    }
    for (int j = t; j < HC * 4; j += 256)          // zero the c=7 pad
        Wsm[j >> 2][j & 3][7] = 0.f;
    if (t < 32) {
        int mtx = t >> 3, c = t & 7;
        const float* B = (mtx == 0) ? bq : (mtx == 1) ? bk : (mtx == 2) ? bv : bs;
        Bsm[mtx][c] = (c < 7) ? B[c] : 0.f;
    }
    __syncthreads();

    int n = blockIdx.x * 256 + t;
    if (n >= N_NODES) return;

    float acc[4][8];
#pragma unroll
    for (int mtx = 0; mtx < 4; mtx++)
#pragma unroll
        for (int c = 0; c < 8; c++) acc[mtx][c] = Bsm[mtx][c];

    const float4* hp = (const float4*)(h + (size_t)n * HC);
#pragma unroll 4
    for (int i4 = 0; i4 < 16; i4++) {
        float4 hv = hp[i4];
        float hx[4] = { hv.x, hv.y, hv.z, hv.w };
#pragma unroll
        for (int e = 0; e < 4; e++) {
            int i = i4 * 4 + e;
#pragma unroll
            for (int mtx = 0; mtx < 4; mtx++) {
                float4 wa = *(const float4*)&Wsm[i][mtx][0];
                float4 wb = *(const float4*)&Wsm[i][mtx][4];
                acc[mtx][0] += hx[e] * wa.x; acc[mtx][1] += hx[e] * wa.y;
                acc[mtx][2] += hx[e] * wa.z; acc[mtx][3] += hx[e] * wa.w;
                acc[mtx][4] += hx[e] * wb.x; acc[mtx][5] += hx[e] * wb.y;
                acc[mtx][6] += hx[e] * wb.z; acc[mtx][7] += hx[e] * wb.w;
            }
        }
    }

    float4* q2v = (float4*)(q2p + (size_t)n * 8);
    q2v[0] = make_float4(acc[0][0], acc[0][1], acc[0][2], acc[0][3]);
    q2v[1] = make_float4(acc[0][4], acc[0][5], acc[0][6], acc[0][7]);
    float4* kvv = (float4*)(kv2 + (size_t)n * 16);
    kvv[0] = make_float4(acc[1][0], acc[1][1], acc[1][2], acc[1][3]);
    kvv[1] = make_float4(acc[1][4], acc[1][5], acc[1][6], acc[1][7]);
    kvv[2] = make_float4(acc[2][0], acc[2][1], acc[2][2], acc[2][3]);
    kvv[3] = make_float4(acc[2][4], acc[2][5], acc[2][6], acc[2][7]);
    float4* s2v = (float4*)(s2p + (size_t)n * 8);
    s2v[0] = make_float4(acc[3][0], acc[3][1], acc[3][2], acc[3][3]);
    s2v[1] = make_float4(acc[3][4], acc[3][5], acc[3][6], acc[3][7]);
}

// ---------------------------------------------------------------- layer2 attention: 4 nodes/wave, 16 lanes/node
__global__ __launch_bounds__(256) void attn2_kernel(
    const int* __restrict__ offs, const uint2* __restrict__ erec,
    const float* __restrict__ q2p, const float* __restrict__ kv2,
    const float* __restrict__ s2p, float* __restrict__ out)
{
    int idx = blockIdx.x * 256 + threadIdx.x;
    int n   = idx >> 4;
    int s   = idx & 15;
    if (n >= N_NODES) return;

    float4 qa = *(const float4*)(q2p + (size_t)n * 8);
    float4 qb = *(const float4*)(q2p + (size_t)n * 8 + 4);
    int beg = offs[n], end = offs[n + 1];

    float m = -3.402823466e38f, l = 0.f, a[OUTF];
#pragma unroll
    for (int c = 0; c < OUTF; c++) a[c] = 0.f;

    for (int i = beg + s; i < end; i += 16) {
        int src = (int)erec[i].x;
        const float4* kvp = (const float4*)(kv2 + (size_t)src * 16);
        float4 ka = kvp[0], kb = kvp[1], va = kvp[2], vb = kvp[3];
        float dot = qa.x * ka.x + qa.y * ka.y + qa.z * ka.z + qa.w * ka.w
                  + qb.x * kb.x + qb.y * kb.y + qb.z * kb.z;
        float logit = dot * 0.37796447300922725f;       // 1/sqrt(7)
        float mn = fmaxf(m, logit);
        float sc = __expf(m - mn);
        float pe = __expf(logit - mn);
        l = l * sc + pe;
        a[0] = a[0] * sc + pe * va.x;
        a[1] = a[1] * sc + pe * va.y;
        a[2] = a[2] * sc + pe * va.z;
        a[3] = a[3] * sc + pe * va.w;
        a[4] = a[4] * sc + pe * vb.x;
        a[5] = a[5] * sc + pe * vb.y;
        a[6] = a[6] * sc + pe * vb.z;
        m = mn;
    }

    if (end > beg) {
        float M = dpp_max16(m);                   // lanes past degree hold -inf
        float sc = __expf(m - M);                 // -inf lanes -> 0
        l *= sc;
#pragma unroll
        for (int c = 0; c < OUTF; c++) a[c] *= sc;
        l = dpp_add16(l);
#pragma unroll
        for (int c = 0; c < OUTF; c++) a[c] = dpp_add16(a[c]);
        if (s == 0) {
            float inv = 1.f / fmaxf(l, 1e-16f);
#pragma unroll
            for (int c = 0; c < OUTF; c++)
                out[(size_t)n * OUTF + c] = a[c] * inv + s2p[(size_t)n * 8 + c];
        }
    } else if (s == 0) {
#pragma unroll
        for (int c = 0; c < OUTF; c++)
            out[(size_t)n * OUTF + c] = s2p[(size_t)n * 8 + c];
    }
}

// ----------------------------------------------------------------
extern "C" void kernel_launch(void* const* d_in, const int* in_sizes, int n_in,
                              void* d_out, int out_size, void* d_ws, size_t ws_size,
                              hipStream_t stream)
{
    const float* x    = (const float*)d_in[0];
    const float* ea   = (const float*)d_in[1];
    const int*   ei   = (const int*)d_in[2];
    const float* Wq1  = (const float*)d_in[3];
    const float* bq1  = (const float*)d_in[4];
    const float* Wk1  = (const float*)d_in[5];
    const float* bk1  = (const float*)d_in[6];
    const float* Wv1  = (const float*)d_in[7];
    const float* bv1  = (const float*)d_in[8];
    const float* We1  = (const float*)d_in[9];
    const float* Ws1  = (const float*)d_in[10];
    const float* bs1  = (const float*)d_in[11];
    const float* Wq2  = (const float*)d_in[12];
    const float* bq2  = (const float*)d_in[13];
    const float* Wk2  = (const float*)d_in[14];
    const float* bk2  = (const float*)d_in[15];
    const float* Wv2  = (const float*)d_in[16];
    const float* bv2  = (const float*)d_in[17];
    const float* Ws2  = (const float*)d_in[18];
    const float* bs2  = (const float*)d_in[19];
    float* out = (float*)d_out;

    // workspace layout; all segments 16B-aligned.
    unsigned short* q1b = (unsigned short*)d_ws;                 // N*64 bf16
    unsigned short* s1b = q1b + (size_t)N_NODES * HC;            // N*64 bf16
    unsigned short* kv1 = s1b + (size_t)N_NODES * HC;            // N*128 bf16
    float*  hbuf = (float*)(kv1 + (size_t)N_NODES * 128);        // N*64 f32
    uint2*  erec = (uint2*)(hbuf + (size_t)N_NODES * HC);        // E x 8B
    uint2*  etmp = erec + N_EDGES;                               // E x 8B
    float*  q2p  = (float*)(etmp + N_EDGES);                     // N*8
    float*  kv2  = q2p + (size_t)N_NODES * 8;                    // N*16
    float*  s2p  = kv2 + (size_t)N_NODES * 16;                   // N*8
    unsigned short* Wt = (unsigned short*)(s2p + (size_t)N_NODES * 8);  // 32768 bf16
    int*    offs  = (int*)(Wt + 4 * HC * IN_F);                  // N+1
    int*    bcnt  = offs + N_NODES + 1;                          // NBK
    int*    bofs2 = bcnt + NBK;                                  // NBK+1
    int*    bcur  = bofs2 + NBK + 1;                             // NBK

    convert_w_kernel<<<(4 * HC * IN_F + 255) / 256, 256, 0, stream>>>(
        Wq1, Wk1, Wv1, Ws1, Wt, bcnt);

    bhist_kernel<<<SCA_BLOCKS, 256, 0, stream>>>(ei, bcnt);
    bscan_kernel<<<1, 256, 0, stream>>>(bcnt, bofs2, bcur);

    proj1_scatterA_kernel<<<SCA_BLOCKS + P1_BLOCKS, 256, 0, stream>>>(
        x, Wt, bq1, bk1, bv1, bs1, q1b, kv1, s1b, ei, ea, bcur, etmp);

    sortB_kernel<<<NBK, 256, 0, stream>>>(bofs2, etmp, erec, offs);

    attn1_kernel<<<(N_NODES * 64 + 255) / 256, 256, 0, stream>>>(
        offs, erec, We1, q1b, kv1, s1b, hbuf);

    proj2_kernel<<<(N_NODES + 255) / 256, 256, 0, stream>>>(
        hbuf, Wq2, bq2, Wk2, bk2, Wv2, bv2, Ws2, bs2, q2p, kv2, s2p);

    attn2_kernel<<<(N_NODES * 16 + 255) / 256, 256, 0, stream>>>(
        offs, erec, q2p, kv2, s2p, out);
}

// Round 24
// 135.344 us; speedup vs baseline: 1.2476x; 1.2476x over previous
//
#include <hip/hip_runtime.h>

// TransformerClassification: 2-layer PyG TransformerConv GNN on MI355X.
// Round 24: REVERT to round-21 exactly (135.7us, passed + replay-stable).
// r22 (runtime-indexed reg cache -> scratch spill) and r23 (compile-time
// cache -> replay race + slower) both failed; widened-scatter abandoned.

#define N_NODES 50000
#define N_EDGES 800000
#define IN_F    128
#define HC      64      // heads*ch layer1
#define NH      4
#define CH      16
#define OUTF    7

#define DPB 100                        // dsts per bucket
#define NBK (N_NODES / DPB)            // 500 buckets
#define SC_EPB 4096
#define SCA_BLOCKS ((N_EDGES + SC_EPB - 1) / SC_EPB)   // 196
#define P1_TILE 32
#define P1_BLOCKS ((N_NODES + P1_TILE - 1) / P1_TILE)  // 1563

typedef __attribute__((ext_vector_type(8))) short bf16x8;
typedef __attribute__((ext_vector_type(4))) float f32x4;

__device__ __forceinline__ unsigned short f2bf(float f) {
    unsigned u = __float_as_uint(f);
    unsigned r = u + 0x7FFFu + ((u >> 16) & 1u);   // round-to-nearest-even
    return (unsigned short)(r >> 16);
}
__device__ __forceinline__ float bflo(unsigned u) { return __uint_as_float(u << 16); }
__device__ __forceinline__ float bfhi(unsigned u) { return __uint_as_float(u & 0xFFFF0000u); }
__device__ __forceinline__ float elu_fast(float x) {
    return x > 0.f ? x : __expf(x) - 1.f;
}

// ---------------- DPP helpers ----------------
__device__ __forceinline__ float dpp_add4(float x) {   // sum within HW quad
    int t;
    t = __builtin_amdgcn_update_dpp(0, __float_as_int(x), 0xB1, 0xF, 0xF, false);
    x += __int_as_float(t);
    t = __builtin_amdgcn_update_dpp(0, __float_as_int(x), 0x4E, 0xF, 0xF, false);
    x += __int_as_float(t);
    return x;
}
__device__ __forceinline__ float dpp_add16(float x) {
    int t;
    t = __builtin_amdgcn_update_dpp(0, __float_as_int(x), 0xB1, 0xF, 0xF, false);
    x += __int_as_float(t);
    t = __builtin_amdgcn_update_dpp(0, __float_as_int(x), 0x4E, 0xF, 0xF, false);
    x += __int_as_float(t);
    t = __builtin_amdgcn_update_dpp(0, __float_as_int(x), 0x124, 0xF, 0xF, false);
    x += __int_as_float(t);
    t = __builtin_amdgcn_update_dpp(0, __float_as_int(x), 0x128, 0xF, 0xF, false);
    x += __int_as_float(t);
    return x;
}
__device__ __forceinline__ float dpp_max16(float x) {
    int t;
    t = __builtin_amdgcn_update_dpp(0, __float_as_int(x), 0xB1, 0xF, 0xF, false);
    x = fmaxf(x, __int_as_float(t));
    t = __builtin_amdgcn_update_dpp(0, __float_as_int(x), 0x4E, 0xF, 0xF, false);
    x = fmaxf(x, __int_as_float(t));
    t = __builtin_amdgcn_update_dpp(0, __float_as_int(x), 0x124, 0xF, 0xF, false);
    x = fmaxf(x, __int_as_float(t));
    t = __builtin_amdgcn_update_dpp(0, __float_as_int(x), 0x128, 0xF, 0xF, false);
    x = fmaxf(x, __int_as_float(t));
    return x;
}

// ---------------------------------------------------------------- convert W -> Wt bf16 (+zero bcnt)
__global__ __launch_bounds__(256) void convert_w_kernel(
    const float* __restrict__ Wq, const float* __restrict__ Wk,
    const float* __restrict__ Wv, const float* __restrict__ Ws,
    unsigned short* __restrict__ Wt, int* __restrict__ bcnt)
{
    int i = blockIdx.x * 256 + threadIdx.x;   // 4*64*128 = 32768
    if (blockIdx.x < 2) {
        int j = blockIdx.x * 256 + threadIdx.x;
        if (j < NBK) bcnt[j] = 0;
    }
    if (i >= 4 * HC * IN_F) return;
    int m   = i >> 13;          // /8192
    int col = (i >> 7) & 63;
    int k   = i & 127;
    const float* W = (m == 0) ? Wq : (m == 1) ? Wk : (m == 2) ? Wv : Ws;
    Wt[i] = f2bf(W[k * HC + col]);
}

// ---------------------------------------------------------------- bucket histogram (LDS-aggregated)
__global__ __launch_bounds__(256) void bhist_kernel(
    const int* __restrict__ ei, int* __restrict__ bcnt)
{
    __shared__ int cnt[NBK];
    const int t = threadIdx.x;
    const int e0 = blockIdx.x * SC_EPB;
    const int e1 = (e0 + SC_EPB < N_EDGES) ? e0 + SC_EPB : N_EDGES;
    for (int j = t; j < NBK; j += 256) cnt[j] = 0;
    __syncthreads();
    for (int e = e0 + t; e < e1; e += 256)
        atomicAdd(&cnt[ei[N_EDGES + e] / DPB], 1);
    __syncthreads();
    for (int j = t; j < NBK; j += 256)
        if (cnt[j]) atomicAdd(&bcnt[j], cnt[j]);
}

// ---------------------------------------------------------------- bucket scan (1 block, 500 elems)
__global__ __launch_bounds__(256) void bscan_kernel(
    const int* __restrict__ bcnt, int* __restrict__ bofs2, int* __restrict__ bcur)
{
    __shared__ int partial[256];
    const int t = threadIdx.x;
    const int b0 = t * 2;
    int c0 = (b0     < NBK) ? bcnt[b0]     : 0;
    int c1 = (b0 + 1 < NBK) ? bcnt[b0 + 1] : 0;
    int s = c0 + c1;
    partial[t] = s;
    __syncthreads();
    for (int d = 1; d < 256; d <<= 1) {
        int u = (t >= d) ? partial[t - d] : 0;
        __syncthreads();
        partial[t] += u;
        __syncthreads();
    }
    int run = partial[t] - s;
    if (b0 < NBK)     { bofs2[b0]     = run;      bcur[b0]     = run; }
    if (b0 + 1 < NBK) { bofs2[b0 + 1] = run + c0; bcur[b0 + 1] = run + c0; }
    if (t == 255) bofs2[NBK] = N_EDGES;
}

// ---------------------------------------------------------------- fused: scatterA (blocks 0..195) | proj1 MFMA
// Scatter blocks FIRST so the memory-bound phase runs under the MFMA stream.
// proj: 32 nodes x 256 cols per block (2 M-tiles); q,s -> bf16; k,v -> kv1.
__global__ __launch_bounds__(256) void proj1_scatterA_kernel(
    const float* __restrict__ x, const unsigned short* __restrict__ Wt,
    const float* __restrict__ bq, const float* __restrict__ bk,
    const float* __restrict__ bv, const float* __restrict__ bs,
    unsigned short* __restrict__ q1b, unsigned short* __restrict__ kv1,
    unsigned short* __restrict__ s1b,
    const int* __restrict__ ei, const float* __restrict__ ea,
    int* __restrict__ bcur, uint2* __restrict__ etmp)
{
    __shared__ unsigned short xs[P1_TILE][136];
    __shared__ int cnt[NBK];
    __shared__ int base[NBK];
    const int t = threadIdx.x;

    if (blockIdx.x < SCA_BLOCKS) {
        const int e0 = blockIdx.x * SC_EPB;
        const int e1 = (e0 + SC_EPB < N_EDGES) ? e0 + SC_EPB : N_EDGES;
        for (int j = t; j < NBK; j += 256) cnt[j] = 0;
        __syncthreads();
        for (int e = e0 + t; e < e1; e += 256)
            atomicAdd(&cnt[ei[N_EDGES + e] / DPB], 1);
        __syncthreads();
        for (int j = t; j < NBK; j += 256) {
            int c = cnt[j];
            if (c) base[j] = atomicAdd(&bcur[j], c);
            cnt[j] = 0;
        }
        __syncthreads();
        for (int e = e0 + t; e < e1; e += 256) {
            int d = ei[N_EDGES + e];
            int s = ei[e];
            int b = d / DPB;
            int li = atomicAdd(&cnt[b], 1);
            uint2 r;
            r.x = (unsigned)s | ((unsigned)d << 16);
            r.y = (unsigned)f2bf(ea[(size_t)e * 2])
                | ((unsigned)f2bf(ea[(size_t)e * 2 + 1]) << 16);
            etmp[base[b] + li] = r;
        }
        return;
    }

    const int w = t >> 6, lane = t & 63;
    const int n0 = (blockIdx.x - SCA_BLOCKS) * P1_TILE;
    const int col16 = lane & 15, kg = lane >> 4;

    // B-fragments: 4 k-chunks x 4 n-tiles (reused across both M-tiles)
    bf16x8 bfrag[4][4];
#pragma unroll
    for (int tt = 0; tt < 4; tt++) {
        const unsigned short* bp = Wt + ((size_t)(w * 64 + tt * 16 + col16) * IN_F) + 8 * kg;
#pragma unroll
        for (int kc = 0; kc < 4; kc++)
            bfrag[kc][tt] = *(const bf16x8*)(bp + kc * 32);
    }

    // stage 32 x-rows as bf16 (1 row-sixteenth per thread), guard tail
    {
        int row = t >> 3, cg = (t & 7) * 16;
        uint4 pk0 = make_uint4(0, 0, 0, 0), pk1 = make_uint4(0, 0, 0, 0);
        if (n0 + row < N_NODES) {
            const float* xp = x + (size_t)(n0 + row) * IN_F + cg;
            float4 f0 = *(const float4*)xp;
            float4 f1 = *(const float4*)(xp + 4);
            float4 f2 = *(const float4*)(xp + 8);
            float4 f3 = *(const float4*)(xp + 12);
            pk0.x = f2bf(f0.x) | ((unsigned)f2bf(f0.y) << 16);
            pk0.y = f2bf(f0.z) | ((unsigned)f2bf(f0.w) << 16);
            pk0.z = f2bf(f1.x) | ((unsigned)f2bf(f1.y) << 16);
            pk0.w = f2bf(f1.z) | ((unsigned)f2bf(f1.w) << 16);
            pk1.x = f2bf(f2.x) | ((unsigned)f2bf(f2.y) << 16);
            pk1.y = f2bf(f2.z) | ((unsigned)f2bf(f2.w) << 16);
            pk1.z = f2bf(f3.x) | ((unsigned)f2bf(f3.y) << 16);
            pk1.w = f2bf(f3.z) | ((unsigned)f2bf(f3.w) << 16);
        }
        *(uint4*)&xs[row][cg]     = pk0;
        *(uint4*)&xs[row][cg + 8] = pk1;
    }
    __syncthreads();

    f32x4 acc[2][4] = { { {0,0,0,0}, {0,0,0,0}, {0,0,0,0}, {0,0,0,0} },
                        { {0,0,0,0}, {0,0,0,0}, {0,0,0,0}, {0,0,0,0} } };
#pragma unroll
    for (int kc = 0; kc < 4; kc++) {
        bf16x8 a0 = *(const bf16x8*)&xs[col16][kc * 32 + 8 * kg];
        bf16x8 a1 = *(const bf16x8*)&xs[16 + col16][kc * 32 + 8 * kg];
#pragma unroll
        for (int tt = 0; tt < 4; tt++) {
            acc[0][tt] = __builtin_amdgcn_mfma_f32_16x16x32_bf16(a0, bfrag[kc][tt], acc[0][tt], 0, 0, 0);
            acc[1][tt] = __builtin_amdgcn_mfma_f32_16x16x32_bf16(a1, bfrag[kc][tt], acc[1][tt], 0, 0, 0);
        }
    }

    if (w == 0 || w == 3) {
        const float* Bm = (w == 0) ? bq : bs;
        unsigned short* Om = (w == 0) ? q1b : s1b;
#pragma unroll
        for (int mt = 0; mt < 2; mt++)
#pragma unroll
        for (int tt = 0; tt < 4; tt++) {
            int col = tt * 16 + col16;
            float bias = Bm[col];
#pragma unroll
            for (int r = 0; r < 4; r++) {
                int node = n0 + mt * 16 + kg * 4 + r;
                if (node < N_NODES)
                    Om[(size_t)node * HC + col] = f2bf(acc[mt][tt][r] + bias);
            }
        }
    } else {
        const float* Bm = (w == 1) ? bk : bv;
        const int cbase = (w == 1) ? 0 : 64;
#pragma unroll
        for (int mt = 0; mt < 2; mt++)
#pragma unroll
        for (int tt = 0; tt < 4; tt++) {
            int col = tt * 16 + col16;
            float bias = Bm[col];
#pragma unroll
            for (int r = 0; r < 4; r++) {
                int node = n0 + mt * 16 + kg * 4 + r;
                if (node < N_NODES)
                    kv1[(size_t)node * 128 + cbase + col] = f2bf(acc[mt][tt][r] + bias);
            }
        }
    }
}

// ---------------------------------------------------------------- scatter phase B: per-dst offs + exact placement
__global__ __launch_bounds__(256) void sortB_kernel(
    const int* __restrict__ bofs2, const uint2* __restrict__ etmp,
    uint2* __restrict__ erec, int* __restrict__ offs)
{
    __shared__ int deg[DPB];
    __shared__ int pre[DPB];
    __shared__ int cur[DPB];
    const int t = threadIdx.x;
    const int b = blockIdx.x;
    const int dlo = b * DPB;
    const int rbeg = bofs2[b], rend = bofs2[b + 1];

    if (t < DPB) deg[t] = 0;
    __syncthreads();
    for (int i = rbeg + t; i < rend; i += 256)
        atomicAdd(&deg[(int)(etmp[i].x >> 16) - dlo], 1);
    __syncthreads();
    if (t < DPB) pre[t] = deg[t];
    __syncthreads();
#pragma unroll
    for (int d = 1; d < DPB; d <<= 1) {
        int u = (t >= d && t < DPB) ? pre[t - d] : 0;
        __syncthreads();
        if (t < DPB) pre[t] += u;
        __syncthreads();
    }
    if (t < DPB) {
        int o = rbeg + pre[t] - deg[t];
        offs[dlo + t] = o;
        cur[t] = o;
    }
    if (b == NBK - 1 && t == 0) offs[N_NODES] = N_EDGES;
    __syncthreads();
    for (int i = rbeg + t; i < rend; i += 256) {
        uint2 r = etmp[i];
        int d = (int)(r.x >> 16) - dlo;
        int pos = atomicAdd(&cur[d], 1);
        uint2 o;
        o.x = r.x & 0xFFFFu;   // src
        o.y = r.y;             // ea bf16x2
        erec[pos] = o;
    }
}

// ---------------------------------------------------------------- layer1 attention: one wave per dst node
// 4 edges/wave, 16 lanes/edge; q/s bf16; ec-hoist + defer-max.
__global__ __launch_bounds__(256) void attn1_kernel(
    const int* __restrict__ offs, const uint2* __restrict__ erec,
    const float* __restrict__ We,
    const unsigned short* __restrict__ q1b, const unsigned short* __restrict__ kv1,
    const unsigned short* __restrict__ s1b, float* __restrict__ h)
{
    int n    = (blockIdx.x * 256 + threadIdx.x) >> 6;
    int lane = threadIdx.x & 63;
    if (n >= N_NODES) return;
    const int g = lane >> 4;     // edge slot 0..3
    const int s = lane & 15;     // channel quad: channels 4s..4s+3

    uint2 qraw = *(const uint2*)(q1b + ((size_t)n << 6) + (s << 2));
    const float4 qv = make_float4(bflo(qraw.x), bfhi(qraw.x),
                                  bflo(qraw.y), bfhi(qraw.y));
    const float4 We0 = *(const float4*)(We + s * 4);
    const float4 We1 = *(const float4*)(We + HC + s * 4);

    float qw0 = dpp_add4(qv.x*We0.x + qv.y*We0.y + qv.z*We0.z + qv.w*We0.w);
    float qw1 = dpp_add4(qv.x*We1.x + qv.y*We1.y + qv.z*We1.z + qv.w*We1.w);

    const int beg = offs[n], end = offs[n + 1];
    float m = -3.402823466e38f, l = 0.f, A0 = 0.f, A1 = 0.f;
    float4 acc = make_float4(0.f, 0.f, 0.f, 0.f);

    for (int base = beg; base < end; base += 4) {
        int i = base + g;
        bool valid = (i < end);
        uint2 r = erec[valid ? i : beg];
        int src = (int)r.x;
        float ea0 = bflo(r.y), ea1 = bfhi(r.y);
        const unsigned short* kvp = kv1 + ((size_t)src << 7) + (s << 2);
        uint2 kraw = *(const uint2*)kvp;
        uint2 vraw = *(const uint2*)(kvp + 64);
        float k0 = bflo(kraw.x), k1 = bfhi(kraw.x);
        float k2 = bflo(kraw.y), k3 = bfhi(kraw.y);
        float dot = qv.x*k0 + qv.y*k1 + qv.z*k2 + qv.w*k3;
        dot = dpp_add4(dot);                      // head dot (16 channels)
        float logit = valid ? (dot + ea0 * qw0 + ea1 * qw1) * 0.25f
                            : -3.402823466e38f;   // 1/sqrt(16)
        if (__any(logit > m + 8.f)) {             // defer-max: rare path
            float mn = fmaxf(m, logit);
            float sm = __expf(m - mn);
            l *= sm; A0 *= sm; A1 *= sm;
            acc.x *= sm; acc.y *= sm; acc.z *= sm; acc.w *= sm;
            m = mn;
        }
        float pe = valid ? __expf(logit - m) : 0.f;   // bounded by e^8
        l += pe;
        float v0 = bflo(vraw.x), v1 = bfhi(vraw.x);
        float v2 = bflo(vraw.y), v3 = bfhi(vraw.y);
        acc.x += pe * v0; acc.y += pe * v1;
        acc.z += pe * v2; acc.w += pe * v3;
        A0 += pe * ea0;  A1 += pe * ea1;
    }

    if (end > beg) {
        float M = fmaxf(m, __shfl_xor(m, 16));
        M = fmaxf(M, __shfl_xor(M, 32));
        float sc = __expf(m - M);                 // empty group: -inf -> 0
        l *= sc; A0 *= sc; A1 *= sc;
        acc.x *= sc; acc.y *= sc; acc.z *= sc; acc.w *= sc;
        l  += __shfl_xor(l, 16);   l  += __shfl_xor(l, 32);
        A0 += __shfl_xor(A0, 16);  A0 += __shfl_xor(A0, 32);
        A1 += __shfl_xor(A1, 16);  A1 += __shfl_xor(A1, 32);
        acc.x += __shfl_xor(acc.x, 16); acc.x += __shfl_xor(acc.x, 32);
        acc.y += __shfl_xor(acc.y, 16); acc.y += __shfl_xor(acc.y, 32);
        acc.z += __shfl_xor(acc.z, 16); acc.z += __shfl_xor(acc.z, 32);
        acc.w += __shfl_xor(acc.w, 16); acc.w += __shfl_xor(acc.w, 32);
        if (lane < 16) {
            float inv = 1.f / l;
            uint2 sraw = *(const uint2*)(s1b + ((size_t)n << 6) + (s << 2));
            float4 o;
            o.x = elu_fast((acc.x + A0 * We0.x + A1 * We1.x) * inv + bflo(sraw.x));
            o.y = elu_fast((acc.y + A0 * We0.y + A1 * We1.y) * inv + bfhi(sraw.x));
            o.z = elu_fast((acc.z + A0 * We0.z + A1 * We1.z) * inv + bflo(sraw.y));
            o.w = elu_fast((acc.w + A0 * We0.w + A1 * We1.w) * inv + bfhi(sraw.y));
            *(float4*)(h + (size_t)n * HC + s * 4) = o;
        }
    } else if (lane < 16) {
        uint2 sraw = *(const uint2*)(s1b + ((size_t)n << 6) + (s << 2));
        float4 o;
        o.x = elu_fast(bflo(sraw.x));
        o.y = elu_fast(bfhi(sraw.x));
        o.z = elu_fast(bflo(sraw.y));
        o.w = elu_fast(bfhi(sraw.y));
        *(float4*)(h + (size_t)n * HC + s * 4) = o;
    }
}

// ---------------------------------------------------------------- layer2 node projections (64 -> 28), thread-per-node
__global__ __launch_bounds__(256) void proj2_kernel(
    const float* __restrict__ h,
    const float* __restrict__ Wq, const float* __restrict__ bq,
    const float* __restrict__ Wk, const float* __restrict__ bk,
    const float* __restrict__ Wv, const float* __restrict__ bv,
    const float* __restrict__ Ws, const float* __restrict__ bs,
    float* __restrict__ q2p, float* __restrict__ kv2, float* __restrict__ s2p)
{
    __shared__ float Wsm[HC][4][8];   // 8 KB
    __shared__ float Bsm[4][8];
    const int t = threadIdx.x;

    for (int j = t; j < HC * 28; j += 256) {
        int i = j / 28, r = j % 28, mtx = r / 7, c = r % 7;
        const float* W = (mtx == 0) ? Wq : (mtx == 1) ? Wk : (mtx == 2) ? Wv : Ws;
        Wsm[i][mtx][c] = W[i * OUTF + c];
    }
    for (int j = t; j < HC * 4; j += 256)          // zero the c=7 pad
        Wsm[j >> 2][j & 3][7] = 0.f;
    if (t < 32) {
        int mtx = t >> 3, c = t & 7;
        const float* B = (mtx == 0) ? bq : (mtx == 1) ? bk : (mtx == 2) ? bv : bs;
        Bsm[mtx][c] = (c < 7) ? B[c] : 0.f;
    }
    __syncthreads();

    int n = blockIdx.x * 256 + t;
    if (n >= N_NODES) return;

    float acc[4][8];
#pragma unroll
    for (int mtx = 0; mtx < 4; mtx++)
#pragma unroll
        for (int c = 0; c < 8; c++) acc[mtx][c] = Bsm[mtx][c];

    const float4* hp = (const float4*)(h + (size_t)n * HC);
#pragma unroll 4
    for (int i4 = 0; i4 < 16; i4++) {
        float4 hv = hp[i4];
        float hx[4] = { hv.x, hv.y, hv.z, hv.w };
#pragma unroll
        for (int e = 0; e < 4; e++) {
            int i = i4 * 4 + e;
#pragma unroll
            for (int mtx = 0; mtx < 4; mtx++) {
                float4 wa = *(const float4*)&Wsm[i][mtx][0];
                float4 wb = *(const float4*)&Wsm[i][mtx][4];
                acc[mtx][0] += hx[e] * wa.x; acc[mtx][1] += hx[e] * wa.y;
                acc[mtx][2] += hx[e] * wa.z; acc[mtx][3] += hx[e] * wa.w;
                acc[mtx][4] += hx[e] * wb.x; acc[mtx][5] += hx[e] * wb.y;
                acc[mtx][6] += hx[e] * wb.z; acc[mtx][7] += hx[e] * wb.w;
            }
        }
    }

    float4* q2v = (float4*)(q2p + (size_t)n * 8);
    q2v[0] = make_float4(acc[0][0], acc[0][1], acc[0][2], acc[0][3]);
    q2v[1] = make_float4(acc[0][4], acc[0][5], acc[0][6], acc[0][7]);
    float4* kvv = (float4*)(kv2 + (size_t)n * 16);
    kvv[0] = make_float4(acc[1][0], acc[1][1], acc[1][2], acc[1][3]);
    kvv[1] = make_float4(acc[1][4], acc[1][5], acc[1][6], acc[1][7]);
    kvv[2] = make_float4(acc[2][0], acc[2][1], acc[2][2], acc[2][3]);
    kvv[3] = make_float4(acc[2][4], acc[2][5], acc[2][6], acc[2][7]);
    float4* s2v = (float4*)(s2p + (size_t)n * 8);
    s2v[0] = make_float4(acc[3][0], acc[3][1], acc[3][2], acc[3][3]);
    s2v[1] = make_float4(acc[3][4], acc[3][5], acc[3][6], acc[3][7]);
}

// ---------------------------------------------------------------- layer2 attention: 4 nodes/wave, 16 lanes/node
__global__ __launch_bounds__(256) void attn2_kernel(
    const int* __restrict__ offs, const uint2* __restrict__ erec,
    const float* __restrict__ q2p, const float* __restrict__ kv2,
    const float* __restrict__ s2p, float* __restrict__ out)
{
    int idx = blockIdx.x * 256 + threadIdx.x;
    int n   = idx >> 4;
    int s   = idx & 15;
    if (n >= N_NODES) return;

    float4 qa = *(const float4*)(q2p + (size_t)n * 8);
    float4 qb = *(const float4*)(q2p + (size_t)n * 8 + 4);
    int beg = offs[n], end = offs[n + 1];

    float m = -3.402823466e38f, l = 0.f, a[OUTF];
#pragma unroll
    for (int c = 0; c < OUTF; c++) a[c] = 0.f;

    for (int i = beg + s; i < end; i += 16) {
        int src = (int)erec[i].x;
        const float4* kvp = (const float4*)(kv2 + (size_t)src * 16);
        float4 ka = kvp[0], kb = kvp[1], va = kvp[2], vb = kvp[3];
        float dot = qa.x * ka.x + qa.y * ka.y + qa.z * ka.z + qa.w * ka.w
                  + qb.x * kb.x + qb.y * kb.y + qb.z * kb.z;
        float logit = dot * 0.37796447300922725f;       // 1/sqrt(7)
        float mn = fmaxf(m, logit);
        float sc = __expf(m - mn);
        float pe = __expf(logit - mn);
        l = l * sc + pe;
        a[0] = a[0] * sc + pe * va.x;
        a[1] = a[1] * sc + pe * va.y;
        a[2] = a[2] * sc + pe * va.z;
        a[3] = a[3] * sc + pe * va.w;
        a[4] = a[4] * sc + pe * vb.x;
        a[5] = a[5] * sc + pe * vb.y;
        a[6] = a[6] * sc + pe * vb.z;
        m = mn;
    }

    if (end > beg) {
        float M = dpp_max16(m);                   // lanes past degree hold -inf
        float sc = __expf(m - M);                 // -inf lanes -> 0
        l *= sc;
#pragma unroll
        for (int c = 0; c < OUTF; c++) a[c] *= sc;
        l = dpp_add16(l);
#pragma unroll
        for (int c = 0; c < OUTF; c++) a[c] = dpp_add16(a[c]);
        if (s == 0) {
            float inv = 1.f / fmaxf(l, 1e-16f);
#pragma unroll
            for (int c = 0; c < OUTF; c++)
                out[(size_t)n * OUTF + c] = a[c] * inv + s2p[(size_t)n * 8 + c];
        }
    } else if (s == 0) {
#pragma unroll
        for (int c = 0; c < OUTF; c++)
            out[(size_t)n * OUTF + c] = s2p[(size_t)n * 8 + c];
    }
}

// ----------------------------------------------------------------
extern "C" void kernel_launch(void* const* d_in, const int* in_sizes, int n_in,
                              void* d_out, int out_size, void* d_ws, size_t ws_size,
                              hipStream_t stream)
{
    const float* x    = (const float*)d_in[0];
    const float* ea   = (const float*)d_in[1];
    const int*   ei   = (const int*)d_in[2];
    const float* Wq1  = (const float*)d_in[3];
    const float* bq1  = (const float*)d_in[4];
    const float* Wk1  = (const float*)d_in[5];
    const float* bk1  = (const float*)d_in[6];
    const float* Wv1  = (const float*)d_in[7];
    const float* bv1  = (const float*)d_in[8];
    const float* We1  = (const float*)d_in[9];
    const float* Ws1  = (const float*)d_in[10];
    const float* bs1  = (const float*)d_in[11];
    const float* Wq2  = (const float*)d_in[12];
    const float* bq2  = (const float*)d_in[13];
    const float* Wk2  = (const float*)d_in[14];
    const float* bk2  = (const float*)d_in[15];
    const float* Wv2  = (const float*)d_in[16];
    const float* bv2  = (const float*)d_in[17];
    const float* Ws2  = (const float*)d_in[18];
    const float* bs2  = (const float*)d_in[19];
    float* out = (float*)d_out;

    // workspace layout; all segments 16B-aligned.
    unsigned short* q1b = (unsigned short*)d_ws;                 // N*64 bf16
    unsigned short* s1b = q1b + (size_t)N_NODES * HC;            // N*64 bf16
    unsigned short* kv1 = s1b + (size_t)N_NODES * HC;            // N*128 bf16
    float*  hbuf = (float*)(kv1 + (size_t)N_NODES * 128);        // N*64 f32
    uint2*  erec = (uint2*)(hbuf + (size_t)N_NODES * HC);        // E x 8B
    uint2*  etmp = erec + N_EDGES;                               // E x 8B
    float*  q2p  = (float*)(etmp + N_EDGES);                     // N*8
    float*  kv2  = q2p + (size_t)N_NODES * 8;                    // N*16
    float*  s2p  = kv2 + (size_t)N_NODES * 16;                   // N*8
    unsigned short* Wt = (unsigned short*)(s2p + (size_t)N_NODES * 8);  // 32768 bf16
    int*    offs  = (int*)(Wt + 4 * HC * IN_F);                  // N+1
    int*    bcnt  = offs + N_NODES + 1;                          // NBK
    int*    bofs2 = bcnt + NBK;                                  // NBK+1
    int*    bcur  = bofs2 + NBK + 1;                             // NBK

    convert_w_kernel<<<(4 * HC * IN_F + 255) / 256, 256, 0, stream>>>(
        Wq1, Wk1, Wv1, Ws1, Wt, bcnt);

    bhist_kernel<<<SCA_BLOCKS, 256, 0, stream>>>(ei, bcnt);
    bscan_kernel<<<1, 256, 0, stream>>>(bcnt, bofs2, bcur);

    proj1_scatterA_kernel<<<SCA_BLOCKS + P1_BLOCKS, 256, 0, stream>>>(
        x, Wt, bq1, bk1, bv1, bs1, q1b, kv1, s1b, ei, ea, bcur, etmp);

    sortB_kernel<<<NBK, 256, 0, stream>>>(bofs2, etmp, erec, offs);

    attn1_kernel<<<(N_NODES * 64 + 255) / 256, 256, 0, stream>>>(
        offs, erec, We1, q1b, kv1, s1b, hbuf);

    proj2_kernel<<<(N_NODES + 255) / 256, 256, 0, stream>>>(
        hbuf, Wq2, bq2, Wk2, bk2, Wv2, bv2, Ws2, bs2, q2p, kv2, s2p);

    attn2_kernel<<<(N_NODES * 16 + 255) / 256, 256, 0, stream>>>(
        offs, erec, q2p, kv2, s2p, out);
}